// Round 5
// baseline (180.738 us; speedup 1.0000x reference)
//
#include <hip/hip_runtime.h>

// HellingerDistance: out[n][m] = 0.5*(rowsum_a[n] + rowsum_b[m]) - sqrt(a[n])·sqrt(b[m])
// N = M = 8192, D = 1024, f32 in/out.
// Round 5: 256x256/BK=64/8-wave GEMM with 4-phase software-pipelined tile body:
// per phase {issue ds_reads of next fragment group | counted lgkmcnt | 16 MFMA}.
// Staging skeleton unchanged from round 4 (2-deep prefetch, vmcnt(8), both-sides
// XOR swizzle, burst stage after read-complete barrier).

#define NM 8192
#define DD 1024
#define NT 16  // K-tiles of 64

typedef __attribute__((ext_vector_type(8))) short bf16x8;
typedef __attribute__((ext_vector_type(4))) float f32x4;

#define AS1 __attribute__((address_space(1)))
#define AS3 __attribute__((address_space(3)))

#define SCHED0 __builtin_amdgcn_sched_barrier(0)
#define WAIT_LGKM(n) do { SCHED0; asm volatile("s_waitcnt lgkmcnt(" #n ")" ::: "memory"); SCHED0; } while (0)
#define WAIT_VM(n)   do { SCHED0; asm volatile("s_waitcnt vmcnt(" #n ")" ::: "memory"); SCHED0; } while (0)

// f32 -> bf16 round-to-nearest-even (inputs positive, no NaN/Inf)
static __device__ __forceinline__ unsigned short f2bf(float f) {
  unsigned int u = __float_as_uint(f);
  u += 0x7FFFu + ((u >> 16) & 1u);
  return (unsigned short)(u >> 16);
}

// ---------------- kernel 1: sqrt -> bf16, exact f32 rowsums ----------------
__global__ __launch_bounds__(256)
void hell_prep(const float* __restrict__ A, const float* __restrict__ B,
               unsigned short* __restrict__ SA, unsigned short* __restrict__ SB,
               float* __restrict__ RA, float* __restrict__ RB) {
  __shared__ float wsum[4];
  const int row = blockIdx.x & (NM - 1);
  const bool isB = blockIdx.x >= NM;
  const float* src = (isB ? B : A) + (size_t)row * DD;
  unsigned short* dst = (isB ? SB : SA) + (size_t)row * DD;
  const int t = threadIdx.x;
  const float4 v = ((const float4*)src)[t];
  ushort4 p;
  p.x = f2bf(sqrtf(v.x)); p.y = f2bf(sqrtf(v.y));
  p.z = f2bf(sqrtf(v.z)); p.w = f2bf(sqrtf(v.w));
  ((ushort4*)dst)[t] = p;
  float s = (v.x + v.y) + (v.z + v.w);
#pragma unroll
  for (int m = 1; m < 64; m <<= 1) s += __shfl_xor(s, m, 64);
  if ((t & 63) == 0) wsum[t >> 6] = s;
  __syncthreads();
  if (t == 0) (isB ? RB : RA)[row] = wsum[0] + wsum[1] + wsum[2] + wsum[3];
}

// ---------------- kernel 2: 256^2 4-phase pipelined bf16 GEMM --------------
__global__ __launch_bounds__(512, 2)
void hell_gemm4(const unsigned short* __restrict__ SA,
                const unsigned short* __restrict__ SB,
                const float* __restrict__ RA, const float* __restrict__ RB,
                float* __restrict__ C) {
  __shared__ __attribute__((aligned(16))) char lds[131072];

  const int t = threadIdx.x;
  const int lane = t & 63;
  const int wave = t >> 6;
  const int wm = wave >> 2;   // 0..1 -> rows wm*128
  const int wn = wave & 3;    // 0..3 -> cols wn*64

  // bijective XCD swizzle: nwg = 1024, 8 XCDs, chunk = 128
  const int wg = blockIdx.x;
  const int s = (wg & 7) * 128 + (wg >> 3);
  const int brow = (s >> 5) * 256;
  const int bcol = (s & 31) * 256;

  // staging: thread t covers LDS row (t>>3) of each 64-row group, chunk t&7.
  // global source chunk pre-swizzled so linear LDS dest == swizzled content.
  const int sw = ((t >> 3) & 7) ^ (t & 7);
  const unsigned short* ga = SA + (size_t)(brow + (t >> 3)) * DD + sw * 8;
  const unsigned short* gb = SB + (size_t)(bcol + (t >> 3)) * DD + sw * 8;

  const int hi = lane >> 4;   // 0..3
  const int lo = lane & 15;   // fragment row within 16
  const int x7 = lane & 7;    // row&7 for swizzled reads

  f32x4 acc[8][4];
#pragma unroll
  for (int m = 0; m < 8; ++m)
#pragma unroll
    for (int n = 0; n < 4; ++n) acc[m][n] = (f32x4){0.f, 0.f, 0.f, 0.f};

  bf16x8 A0[2][2], A1[2][2];  // A-quadrant reg sets (ping-pong per phase)
  bf16x8 B0[4][2], B1[4][2];  // B full-tile reg sets (ping-pong per tile)

#define STAGE_TILE(KT2, CURB)                                                   \
  do {                                                                          \
    const size_t ko_ = (size_t)(KT2) * 64;                                      \
    _Pragma("unroll")                                                           \
    for (int i_ = 0; i_ < 4; ++i_)                                              \
      __builtin_amdgcn_global_load_lds(                                         \
          (const AS1 unsigned int*)(ga + (size_t)(i_ * 64) * DD + ko_),         \
          (AS3 unsigned int*)(lds + (CURB)*65536 + i_ * 8192 + t * 16), 16, 0, 0); \
    _Pragma("unroll")                                                           \
    for (int i_ = 0; i_ < 4; ++i_)                                              \
      __builtin_amdgcn_global_load_lds(                                         \
          (const AS1 unsigned int*)(gb + (size_t)(i_ * 64) * DD + ko_),         \
          (AS3 unsigned int*)(lds + (CURB)*65536 + 32768 + i_ * 8192 + t * 16), 16, 0, 0); \
  } while (0)

#define LDB(BS, Bb)                                                             \
  do {                                                                          \
    _Pragma("unroll")                                                           \
    for (int n_ = 0; n_ < 4; ++n_) {                                            \
      const char* rb_ = (Bb) + (wn * 64 + n_ * 16 + lo) * 128;                  \
      _Pragma("unroll")                                                         \
      for (int k_ = 0; k_ < 2; ++k_)                                            \
        BS[n_][k_] = *(const bf16x8*)(rb_ + (((k_ * 4 + hi) ^ x7) << 4));       \
    }                                                                           \
  } while (0)

#define LDA(ASet, Ab, q)                                                        \
  do {                                                                          \
    _Pragma("unroll")                                                           \
    for (int m_ = 0; m_ < 2; ++m_) {                                            \
      const char* ra_ = (Ab) + (wm * 128 + ((q) * 2 + m_) * 16 + lo) * 128;     \
      _Pragma("unroll")                                                         \
      for (int k_ = 0; k_ < 2; ++k_)                                            \
        ASet[m_][k_] = *(const bf16x8*)(ra_ + (((k_ * 4 + hi) ^ x7) << 4));     \
    }                                                                           \
  } while (0)

#define MFMA_Q(q, ASet, BS)                                                     \
  do {                                                                          \
    __builtin_amdgcn_s_setprio(1);                                              \
    _Pragma("unroll")                                                           \
    for (int m_ = 0; m_ < 2; ++m_)                                              \
      _Pragma("unroll")                                                         \
      for (int n_ = 0; n_ < 4; ++n_)                                            \
        _Pragma("unroll")                                                       \
        for (int k_ = 0; k_ < 2; ++k_)                                          \
          acc[(q) * 2 + m_][n_] = __builtin_amdgcn_mfma_f32_16x16x32_bf16(      \
              ASet[m_][k_], BS[n_][k_], acc[(q) * 2 + m_][n_], 0, 0, 0);        \
    __builtin_amdgcn_s_setprio(0);                                              \
  } while (0)

// 4-phase pipelined tile: reads run one phase ahead of MFMA; buffer is stable
// for the whole tile so no intra-tile barriers; counted lgkmcnt per phase.
#define TILE(tbuf, BLOAD, BPREV, DO_PREV_Q3)                                    \
  do {                                                                          \
    const char* Ab_ = lds + (tbuf)*65536;                                       \
    const char* Bb_ = Ab_ + 32768;                                              \
    /* P0: issue 12 reads (B-tile + A-quad0), overlap prev tile's quad3 */      \
    LDB(BLOAD, Bb_); LDA(A0, Ab_, 0); SCHED0;                                   \
    if (DO_PREV_Q3) MFMA_Q(3, A1, BPREV);                                       \
    SCHED0;                                                                     \
    /* P1 */ LDA(A1, Ab_, 1); WAIT_LGKM(4); MFMA_Q(0, A0, BLOAD); SCHED0;       \
    /* P2 */ LDA(A0, Ab_, 2); WAIT_LGKM(4); MFMA_Q(1, A1, BLOAD); SCHED0;       \
    /* P3 */ LDA(A1, Ab_, 3); WAIT_LGKM(4); MFMA_Q(2, A0, BLOAD); SCHED0;       \
    WAIT_LGKM(0);                                                               \
    __builtin_amdgcn_s_barrier(); /* all waves done reading this buffer */      \
  } while (0)

  // prologue: tile0 -> buf0, tile1 -> buf1; wait tile0 (8 of 16 outstanding)
  STAGE_TILE(0, 0);
  STAGE_TILE(1, 1);
  WAIT_VM(8);
  __builtin_amdgcn_s_barrier();

#pragma unroll 1
  for (int it = 0; it < 8; ++it) {
    // ---- even tile t0 = 2it (buf0): B[t0] -> B0; q3 of t0-1 uses B1 ----
    TILE(0, B0, B1, it != 0);
    if (it < 7) { STAGE_TILE(2 * it + 2, 0); WAIT_VM(8); }
    else        { WAIT_VM(0); }   // drain tile 15's loads before reading buf1
    __builtin_amdgcn_s_barrier();

    // ---- odd tile t1 = 2it+1 (buf1): B[t1] -> B1; q3 of t0 uses B0 ----
    TILE(1, B1, B0, 1);
    if (it < 7) {
      STAGE_TILE(2 * it + 3, 1);
      WAIT_VM(8);                 // tile 2it+2 landed; 2it+3's 8 in flight
      __builtin_amdgcn_s_barrier();
    }
  }
  // final quadrant of tile 15
  MFMA_Q(3, A1, B1);

#undef TILE
#undef MFMA_Q
#undef LDA
#undef LDB
#undef STAGE_TILE

  // epilogue: C/D layout col=lane&15, row=(lane>>4)*4+j
  float hrb[4];
#pragma unroll
  for (int n = 0; n < 4; ++n)
    hrb[n] = 0.5f * RB[bcol + wn * 64 + n * 16 + lo];
#pragma unroll
  for (int m = 0; m < 8; ++m) {
    const int rbase = wm * 128 + m * 16 + hi * 4;
#pragma unroll
    for (int j = 0; j < 4; ++j) {
      const int row = rbase + j;
      const float ha = 0.5f * RA[brow + row];
      float* orow = C + (size_t)(brow + row) * NM + bcol;
#pragma unroll
      for (int n = 0; n < 4; ++n)
        orow[wn * 64 + n * 16 + lo] = ha + hrb[n] - acc[m][n][j];
    }
  }
}

// ---------------- fallback: fused kernel (if ws too small) -----------------
static __device__ __forceinline__ int swz(int row, int colbytes) {
  return (row * 128 + colbytes) ^ ((row & 7) << 4);
}

__global__ __launch_bounds__(256, 2)
void hellinger_fused(const float* __restrict__ A, const float* __restrict__ B,
                     float* __restrict__ C) {
  __shared__ unsigned short As[128 * 64];
  __shared__ unsigned short Bs[128 * 64];
  __shared__ float sA[128];
  __shared__ float sB[128];

  const int t = threadIdx.x;
  const int lane = t & 63;
  const int wave = t >> 6;
  const int wrow = (wave >> 1) * 64;
  const int wcol = (wave & 1) * 64;
  const int brow = blockIdx.y * 128;
  const int bcol = blockIdx.x * 128;
  const int sr = t >> 4;
  const int sc = (t & 15) * 4;

  const float* ap = A + (size_t)(brow + sr) * DD + sc;
  const float* bp = B + (size_t)(bcol + sr) * DD + sc;

  float racc[8], cacc[8];
#pragma unroll
  for (int i = 0; i < 8; ++i) { racc[i] = 0.f; cacc[i] = 0.f; }

  f32x4 acc[4][4];
#pragma unroll
  for (int m = 0; m < 4; ++m)
#pragma unroll
    for (int n = 0; n < 4; ++n) acc[m][n] = (f32x4){0.f, 0.f, 0.f, 0.f};

  for (int kt = 0; kt < DD / 64; ++kt) {
#pragma unroll
    for (int i = 0; i < 8; ++i) {
      const float4 v = *(const float4*)(ap + (size_t)(i * 16) * DD + kt * 64);
      racc[i] += (v.x + v.y) + (v.z + v.w);
      ushort4 p;
      p.x = f2bf(sqrtf(v.x)); p.y = f2bf(sqrtf(v.y));
      p.z = f2bf(sqrtf(v.z)); p.w = f2bf(sqrtf(v.w));
      *(ushort4*)((char*)As + swz(i * 16 + sr, sc * 2)) = p;
    }
#pragma unroll
    for (int i = 0; i < 8; ++i) {
      const float4 v = *(const float4*)(bp + (size_t)(i * 16) * DD + kt * 64);
      cacc[i] += (v.x + v.y) + (v.z + v.w);
      ushort4 p;
      p.x = f2bf(sqrtf(v.x)); p.y = f2bf(sqrtf(v.y));
      p.z = f2bf(sqrtf(v.z)); p.w = f2bf(sqrtf(v.w));
      *(ushort4*)((char*)Bs + swz(i * 16 + sr, sc * 2)) = p;
    }
    __syncthreads();
#pragma unroll
    for (int kk = 0; kk < 2; ++kk) {
      const int koffb = kk * 64 + (lane >> 4) * 16;
      bf16x8 af[4], bfr[4];
#pragma unroll
      for (int m = 0; m < 4; ++m)
        af[m] = *(const bf16x8*)((const char*)As + swz(wrow + m * 16 + (lane & 15), koffb));
#pragma unroll
      for (int n = 0; n < 4; ++n)
        bfr[n] = *(const bf16x8*)((const char*)Bs + swz(wcol + n * 16 + (lane & 15), koffb));
#pragma unroll
      for (int m = 0; m < 4; ++m)
#pragma unroll
        for (int n = 0; n < 4; ++n)
          acc[m][n] = __builtin_amdgcn_mfma_f32_16x16x32_bf16(af[m], bfr[n], acc[m][n], 0, 0, 0);
    }
    __syncthreads();
  }

#pragma unroll
  for (int i = 0; i < 8; ++i) {
#pragma unroll
    for (int mask = 1; mask < 16; mask <<= 1) {
      racc[i] += __shfl_xor(racc[i], mask, 64);
      cacc[i] += __shfl_xor(cacc[i], mask, 64);
    }
  }
  if ((t & 15) == 0) {
#pragma unroll
    for (int i = 0; i < 8; ++i) { sA[i * 16 + sr] = racc[i]; sB[i * 16 + sr] = cacc[i]; }
  }
  __syncthreads();

#pragma unroll
  for (int m = 0; m < 4; ++m) {
    const int rbase = wrow + m * 16 + (lane >> 4) * 4;
#pragma unroll
    for (int j = 0; j < 4; ++j) {
      const int row = rbase + j;
      const float ha = 0.5f * sA[row];
      float* orow = C + (size_t)(brow + row) * NM + bcol;
#pragma unroll
      for (int n = 0; n < 4; ++n) {
        const int col = wcol + n * 16 + (lane & 15);
        orow[col] = ha + 0.5f * sB[col] - acc[m][n][j];
      }
    }
  }
}

extern "C" void kernel_launch(void* const* d_in, const int* in_sizes, int n_in,
                              void* d_out, int out_size, void* d_ws, size_t ws_size,
                              hipStream_t stream) {
  const float* a = (const float*)d_in[0];
  const float* b = (const float*)d_in[1];
  float* out = (float*)d_out;

  const size_t mat_bytes = (size_t)NM * DD * sizeof(unsigned short); // 16 MB
  const size_t need = 2 * mat_bytes + 2 * (size_t)NM * sizeof(float);

  if (ws_size >= need) {
    unsigned short* SA = (unsigned short*)d_ws;
    unsigned short* SB = (unsigned short*)((char*)d_ws + mat_bytes);
    float* RA = (float*)((char*)d_ws + 2 * mat_bytes);
    float* RB = RA + NM;
    hipLaunchKernelGGL(hell_prep, dim3(2 * NM), dim3(256), 0, stream,
                       a, b, SA, SB, RA, RB);
    hipLaunchKernelGGL(hell_gemm4, dim3(32 * 32), dim3(512), 0, stream,
                       SA, SB, RA, RB, out);
  } else {
    dim3 grid(NM / 128, NM / 128);
    hipLaunchKernelGGL(hellinger_fused, grid, dim3(256), 0, stream, a, b, out);
  }
}